// Round 1
// baseline (478.075 us; speedup 1.0000x reference)
//
#include <hip/hip_runtime.h>
#include <hip/hip_bf16.h>

typedef unsigned short u16;
typedef unsigned int u32;

using bf16x8 = __attribute__((ext_vector_type(8))) short;
using f32x4  = __attribute__((ext_vector_type(4))) float;

#define MFMA16(a, b, c) __builtin_amdgcn_mfma_f32_16x16x32_bf16((a), (b), (c), 0, 0, 0)

__device__ __forceinline__ u16 f2bf(float f) {
    u32 u = __builtin_bit_cast(u32, f);
    u = (u + 0x7fffu + ((u >> 16) & 1u)) >> 16;
    return (u16)u;
}

// ---------------------------------------------------------------------------
// Prep kernel:
//  blocks 0..31   : convert Wq (in_proj rows 0..511) and Wo to bf16
//  blocks 32..159 : K/V projection via MFMA:  [K;V] = region @ W2^T + b2
//      K stored as kt[b][h][r][d]  (r-major, d contiguous)
//      V stored as vt[b][h][d][r]  (d-major, r contiguous)  == V^T per head
// ---------------------------------------------------------------------------
__global__ __launch_bounds__(256, 2) void frgca_prep(
    const float* __restrict__ region,
    const float* __restrict__ in_w,
    const float* __restrict__ in_b,
    const float* __restrict__ out_w,
    u16* __restrict__ wq, u16* __restrict__ wo,
    u16* __restrict__ kt, u16* __restrict__ vt)
{
    __shared__ u16 As2[64 * 520];
    const int tid = threadIdx.x;
    const int bid = blockIdx.x;

    if (bid < 32) {
        // weight conversion: 2 x 262144 floats = 131072 float4, 8192 threads, 16 iters
        const float4* w4q = (const float4*)in_w;
        const float4* w4o = (const float4*)out_w;
        int t = bid * 256 + tid;
#pragma unroll
        for (int i = 0; i < 16; ++i) {
            int idx = t + i * 8192;
            float4 v;
            u16* dst;
            if (idx < 65536) { v = w4q[idx]; dst = wq + idx * 4; }
            else             { v = w4o[idx - 65536]; dst = wo + (idx - 65536) * 4; }
            ushort4 o;
            o.x = f2bf(v.x); o.y = f2bf(v.y); o.z = f2bf(v.z); o.w = f2bf(v.w);
            *(ushort4*)dst = o;
        }
        return;
    }

    const int t2 = bid - 32;      // 0..127
    const int b  = t2 >> 2;
    const int nc = t2 & 3;

    // stage region[b] (64x512 fp32) into LDS as bf16
    {
        const float4* r4 = (const float4*)(region + (size_t)b * 64 * 512);
#pragma unroll
        for (int i = 0; i < 32; ++i) {
            int f4  = tid + i * 256;       // 0..8191
            int row = f4 >> 7;
            int c4  = f4 & 127;
            float4 v = r4[f4];
            ushort4 o;
            o.x = f2bf(v.x); o.y = f2bf(v.y); o.z = f2bf(v.z); o.w = f2bf(v.w);
            *(ushort4*)&As2[row * 520 + c4 * 4] = o;
        }
    }
    __syncthreads();

    const int lane = tid & 63, w = tid >> 6;
    const int lo16 = lane & 15, g = lane >> 4;
    const int e0 = nc * 256 + w * 64;

    f32x4 acc[4][4];
#pragma unroll
    for (int mt = 0; mt < 4; ++mt)
#pragma unroll
        for (int nt = 0; nt < 4; ++nt)
            acc[mt][nt] = f32x4{0.f, 0.f, 0.f, 0.f};

    const float* w2 = in_w + 512 * 512;   // rows 512..1535 of in_proj_weight

#pragma unroll 2
    for (int ks = 0; ks < 16; ++ks) {
        const int kc = ks * 32 + 8 * g;
        bf16x8 a[4], bb[4];
#pragma unroll
        for (int mt = 0; mt < 4; ++mt)
            a[mt] = *(const bf16x8*)&As2[(mt * 16 + lo16) * 520 + kc];
#pragma unroll
        for (int nt = 0; nt < 4; ++nt) {
            const int e = e0 + nt * 16 + lo16;
            const float* src = w2 + (size_t)e * 512 + kc;
            float4 v0 = *(const float4*)src;
            float4 v1 = *(const float4*)(src + 4);
            bf16x8 bv;
            bv[0] = (short)f2bf(v0.x); bv[1] = (short)f2bf(v0.y);
            bv[2] = (short)f2bf(v0.z); bv[3] = (short)f2bf(v0.w);
            bv[4] = (short)f2bf(v1.x); bv[5] = (short)f2bf(v1.y);
            bv[6] = (short)f2bf(v1.z); bv[7] = (short)f2bf(v1.w);
            bb[nt] = bv;
        }
#pragma unroll
        for (int mt = 0; mt < 4; ++mt)
#pragma unroll
            for (int nt = 0; nt < 4; ++nt)
                acc[mt][nt] = MFMA16(a[mt], bb[nt], acc[mt][nt]);
    }

#pragma unroll
    for (int nt = 0; nt < 4; ++nt) {
        const int e = e0 + nt * 16 + lo16;
        const float bias = in_b[512 + e];
#pragma unroll
        for (int mt = 0; mt < 4; ++mt)
#pragma unroll
            for (int i = 0; i < 4; ++i) {
                const int r = mt * 16 + 4 * g + i;
                const u16 o = f2bf(acc[mt][nt][i] + bias);
                if (e < 512) {  // K output
                    const int h = e >> 6, d = e & 63;
                    kt[(((size_t)(b * 8 + h)) * 64 + r) * 64 + d] = o;
                } else {        // V output
                    const int e2 = e - 512;
                    const int h = e2 >> 6, d = e2 & 63;
                    vt[(((size_t)(b * 8 + h)) * 64 + d) * 64 + r] = o;
                }
            }
    }
}

// ---------------------------------------------------------------------------
// Main fused kernel. One block = 64 visual tokens of one batch. 8 waves.
// Wave w owns head w (its 64 Q/ctx columns). Phases:
//  P1: Q = visual @ Wq^T + bq              (MFMA, per-wave 64 cols)
//  P2: S^T = K @ Q^T, scale + mask bias, softmax over r (fp32)
//  P3: ctx^T = V^T @ attn^T                (MFMA)
//  P4: out = ctx @ Wo^T + bo + visual      (MFMA, residual)
// LDS regionA (73728B) reused: As[64][520] -> per-wave Qs/Ss [64][72] -> Cs[64][520]
// ---------------------------------------------------------------------------
__global__ __launch_bounds__(512, 2) void frgca_main(
    const float* __restrict__ visual,
    const float* __restrict__ mask,
    const float* __restrict__ in_b,
    const float* __restrict__ out_b,
    const u16* __restrict__ wq, const u16* __restrict__ wo,
    const u16* __restrict__ kt, const u16* __restrict__ vt,
    float* __restrict__ out)
{
    __shared__ char regA[73728];
    __shared__ float Ms[64][65];

    const int tid = threadIdx.x;
    const int w = tid >> 6, lane = tid & 63;
    const int lo16 = lane & 15, g = lane >> 4;
    const int pt = blockIdx.x, b = blockIdx.y;
    const int P0 = pt * 64;
    const size_t vbase = ((size_t)(b * 4096 + P0)) * 512;

    u16* As = (u16*)regA;  // [64][520] bf16

    // ---- stage visual tile (bf16) + mask bias (fp32) ----
    {
        const float4* v4 = (const float4*)(visual + vbase);
#pragma unroll
        for (int i = 0; i < 16; ++i) {
            int f4  = tid + i * 512;       // 0..8191
            int row = f4 >> 7, c4 = f4 & 127;
            float4 v = v4[f4];
            ushort4 o;
            o.x = f2bf(v.x); o.y = f2bf(v.y); o.z = f2bf(v.z); o.w = f2bf(v.w);
            *(ushort4*)&As[row * 520 + c4 * 4] = o;
        }
        const float4* m4 = (const float4*)(mask + ((size_t)(b * 4096 + P0)) * 64);
#pragma unroll
        for (int i = 0; i < 2; ++i) {
            int f4  = tid + i * 512;       // 0..1023
            int row = f4 >> 4, c4 = f4 & 15;
            float4 v = m4[f4];
            float* dst = &Ms[row][c4 * 4];
            dst[0] = (1.0f - v.x) * -1e9f;
            dst[1] = (1.0f - v.y) * -1e9f;
            dst[2] = (1.0f - v.z) * -1e9f;
            dst[3] = (1.0f - v.w) * -1e9f;
        }
    }
    __syncthreads();

    const int e0 = w * 64;

    // ---- P1: Q GEMM ----
    f32x4 acc[4][4];
#pragma unroll
    for (int mt = 0; mt < 4; ++mt)
#pragma unroll
        for (int nt = 0; nt < 4; ++nt)
            acc[mt][nt] = f32x4{0.f, 0.f, 0.f, 0.f};

#pragma unroll 2
    for (int ks = 0; ks < 16; ++ks) {
        const int kc = ks * 32 + 8 * g;
        bf16x8 a[4], bb[4];
#pragma unroll
        for (int mt = 0; mt < 4; ++mt)
            a[mt] = *(const bf16x8*)&As[(mt * 16 + lo16) * 520 + kc];
#pragma unroll
        for (int nt = 0; nt < 4; ++nt)
            bb[nt] = *(const bf16x8*)&wq[((size_t)(e0 + nt * 16 + lo16)) * 512 + kc];
#pragma unroll
        for (int mt = 0; mt < 4; ++mt)
#pragma unroll
            for (int nt = 0; nt < 4; ++nt)
                acc[mt][nt] = MFMA16(a[mt], bb[nt], acc[mt][nt]);
    }
#pragma unroll
    for (int nt = 0; nt < 4; ++nt) {
        const float bq = in_b[e0 + nt * 16 + lo16];
#pragma unroll
        for (int mt = 0; mt < 4; ++mt)
#pragma unroll
            for (int i = 0; i < 4; ++i)
                acc[mt][nt][i] += bq;
    }
    __syncthreads();   // all As reads done; regionA becomes per-wave slices

    // ---- write Q to wave-private LDS slice  Qs[p][d], stride 72 ----
    u16* Qw = (u16*)(regA + w * 9216);
#pragma unroll
    for (int mt = 0; mt < 4; ++mt)
#pragma unroll
        for (int nt = 0; nt < 4; ++nt)
#pragma unroll
            for (int i = 0; i < 4; ++i)
                Qw[(mt * 16 + 4 * g + i) * 72 + (nt * 16 + lo16)] = f2bf(acc[mt][nt][i]);

    // ---- P2: S^T = K @ Q^T ----
    const u16* KtH = kt + ((size_t)(b * 8 + w)) * 64 * 64;   // [r][d]
    f32x4 s[4][4];
#pragma unroll
    for (int mt = 0; mt < 4; ++mt)
#pragma unroll
        for (int nt = 0; nt < 4; ++nt)
            s[mt][nt] = f32x4{0.f, 0.f, 0.f, 0.f};

#pragma unroll
    for (int ks = 0; ks < 2; ++ks) {
        const int kc = ks * 32 + 8 * g;
        bf16x8 ak[4], bq_[4];
#pragma unroll
        for (int mt = 0; mt < 4; ++mt)
            ak[mt] = *(const bf16x8*)&KtH[(mt * 16 + lo16) * 64 + kc];
#pragma unroll
        for (int nt = 0; nt < 4; ++nt)
            bq_[nt] = *(const bf16x8*)&Qw[(nt * 16 + lo16) * 72 + kc];
#pragma unroll
        for (int mt = 0; mt < 4; ++mt)
#pragma unroll
            for (int nt = 0; nt < 4; ++nt)
                s[mt][nt] = MFMA16(ak[mt], bq_[nt], s[mt][nt]);
    }

    // ---- softmax over r (per column p), fp32, then attn->bf16 into slice ----
#pragma unroll
    for (int nt = 0; nt < 4; ++nt) {
        const int p = nt * 16 + lo16;
        float mx = -3.4e38f;
#pragma unroll
        for (int mt = 0; mt < 4; ++mt)
#pragma unroll
            for (int i = 0; i < 4; ++i) {
                float v = s[mt][nt][i] * 0.125f + Ms[p][mt * 16 + 4 * g + i];
                s[mt][nt][i] = v;
                mx = fmaxf(mx, v);
            }
        mx = fmaxf(mx, __shfl_xor(mx, 16));
        mx = fmaxf(mx, __shfl_xor(mx, 32));
        float sum = 0.f;
#pragma unroll
        for (int mt = 0; mt < 4; ++mt)
#pragma unroll
            for (int i = 0; i < 4; ++i) {
                float ev = __expf(s[mt][nt][i] - mx);
                s[mt][nt][i] = ev;
                sum += ev;
            }
        sum += __shfl_xor(sum, 16);
        sum += __shfl_xor(sum, 32);
        const float inv = 1.0f / sum;
#pragma unroll
        for (int mt = 0; mt < 4; ++mt)
#pragma unroll
            for (int i = 0; i < 4; ++i)
                Qw[p * 72 + (mt * 16 + 4 * g + i)] = f2bf(s[mt][nt][i] * inv);
    }

    // ---- P3: ctx^T = V^T @ attn^T ----
    const u16* VtH = vt + ((size_t)(b * 8 + w)) * 64 * 64;   // [d][r]
    f32x4 c_[4][4];
#pragma unroll
    for (int mt = 0; mt < 4; ++mt)
#pragma unroll
        for (int nt = 0; nt < 4; ++nt)
            c_[mt][nt] = f32x4{0.f, 0.f, 0.f, 0.f};

#pragma unroll
    for (int ks = 0; ks < 2; ++ks) {
        const int kc = ks * 32 + 8 * g;
        bf16x8 av[4], bs_[4];
#pragma unroll
        for (int mt = 0; mt < 4; ++mt)
            av[mt] = *(const bf16x8*)&VtH[(mt * 16 + lo16) * 64 + kc];
#pragma unroll
        for (int nt = 0; nt < 4; ++nt)
            bs_[nt] = *(const bf16x8*)&Qw[(nt * 16 + lo16) * 72 + kc];
#pragma unroll
        for (int mt = 0; mt < 4; ++mt)
#pragma unroll
            for (int nt = 0; nt < 4; ++nt)
                c_[mt][nt] = MFMA16(av[mt], bs_[nt], c_[mt][nt]);
    }
    __syncthreads();   // everyone done with private slices; regionA -> Cs

    // ---- stage ctx (bf16) into Cs[p][c], stride 520 ----
    u16* Cs = (u16*)regA;
#pragma unroll
    for (int mt = 0; mt < 4; ++mt)
#pragma unroll
        for (int nt = 0; nt < 4; ++nt)
#pragma unroll
            for (int i = 0; i < 4; ++i) {
                const int d = mt * 16 + 4 * g + i;
                const int p = nt * 16 + lo16;
                Cs[p * 520 + (w * 64 + d)] = f2bf(c_[mt][nt][i]);
            }
    __syncthreads();

    // ---- P4: out = ctx @ Wo^T + bo + visual ----
    f32x4 o_[4][4];
#pragma unroll
    for (int mt = 0; mt < 4; ++mt)
#pragma unroll
        for (int nt = 0; nt < 4; ++nt)
            o_[mt][nt] = f32x4{0.f, 0.f, 0.f, 0.f};

#pragma unroll 2
    for (int ks = 0; ks < 16; ++ks) {
        const int kc = ks * 32 + 8 * g;
        bf16x8 a[4], bb[4];
#pragma unroll
        for (int mt = 0; mt < 4; ++mt)
            a[mt] = *(const bf16x8*)&Cs[(mt * 16 + lo16) * 520 + kc];
#pragma unroll
        for (int nt = 0; nt < 4; ++nt)
            bb[nt] = *(const bf16x8*)&wo[((size_t)(e0 + nt * 16 + lo16)) * 512 + kc];
#pragma unroll
        for (int mt = 0; mt < 4; ++mt)
#pragma unroll
            for (int nt = 0; nt < 4; ++nt)
                o_[mt][nt] = MFMA16(a[mt], bb[nt], o_[mt][nt]);
    }

#pragma unroll
    for (int nt = 0; nt < 4; ++nt) {
        const int e = e0 + nt * 16 + lo16;
        const float bo = out_b[e];
#pragma unroll
        for (int mt = 0; mt < 4; ++mt)
#pragma unroll
            for (int i = 0; i < 4; ++i) {
                const int p = mt * 16 + 4 * g + i;
                const size_t gid = vbase + (size_t)p * 512 + e;
                out[gid] = o_[mt][nt][i] + bo + visual[gid];
            }
    }
}

extern "C" void kernel_launch(void* const* d_in, const int* in_sizes, int n_in,
                              void* d_out, int out_size, void* d_ws, size_t ws_size,
                              hipStream_t stream) {
    const float* visual = (const float*)d_in[0];
    const float* region = (const float*)d_in[1];
    const float* mask   = (const float*)d_in[2];
    const float* in_w   = (const float*)d_in[3];
    const float* in_b   = (const float*)d_in[4];
    const float* out_w  = (const float*)d_in[5];
    const float* out_b  = (const float*)d_in[6];
    float* out = (float*)d_out;

    char* ws = (char*)d_ws;
    u16* wq = (u16*)(ws + 0);        // 512*512 bf16 = 512 KB
    u16* wo = (u16*)(ws + 524288);   // 512 KB
    u16* kt = (u16*)(ws + 1048576);  // 32*8*64*64 bf16 = 2 MB, [b][h][r][d]
    u16* vt = (u16*)(ws + 3145728);  // 2 MB, [b][h][d][r]

    frgca_prep<<<dim3(160), dim3(256), 0, stream>>>(region, in_w, in_b, out_w, wq, wo, kt, vt);
    frgca_main<<<dim3(64, 32), dim3(512), 0, stream>>>(visual, mask, in_b, out_b, wq, wo, kt, vt, out);
}